// Round 1
// baseline (87.052 us; speedup 1.0000x reference)
//
#include <hip/hip_runtime.h>
#include <math.h>

#define NP 64        // particles
#define DD 32        // dims
#define NPAIR (NP*NP)   // 4096
#define NTHREADS 1024

__global__ __launch_bounds__(NTHREADS)
void svgd_kernel(const float* __restrict__ particle,
                 const float* __restrict__ mu,
                 float* __restrict__ out) {
    __shared__ float xs[NP*DD];      // 8 KB
    __shared__ float Ds[NP*DD];      // 8 KB   Ds_j = P(x_j)(mu - x_j)
    __shared__ float sN[NP];         // ||x_i||^2
    __shared__ float muS[DD];
    __shared__ float dist2[NPAIR];   // 16 KB
    __shared__ float sortbuf[NPAIR]; // 16 KB
    __shared__ float denomS;

    const int tid  = threadIdx.x;
    const int grp  = tid >> 5;   // 0..31
    const int lane = tid & 31;   // dimension index

    // ---- load inputs ----
    for (int i = tid; i < NP*DD; i += NTHREADS) xs[i] = particle[i];
    if (tid < DD) muS[tid] = mu[tid];
    __syncthreads();

    // ---- per-particle norms + Ds via 32-lane reductions ----
    for (int rep = 0; rep < 2; ++rep) {
        int i = grp + rep*32;
        float xv = xs[i*DD + lane];
        float mv = muS[lane] - xv;          // (mu - x_i)[lane]
        float ss = xv*xv;
        float tt = xv*mv;
        for (int m = 16; m; m >>= 1) {
            ss += __shfl_xor(ss, m, 32);
            tt += __shfl_xor(tt, m, 32);
        }
        if (lane == 0) sN[i] = ss;
        Ds[i*DD + lane] = mv - xv*(tt/ss);  // P(x_i)(mu-x_i)
    }
    __syncthreads();

    // ---- pairwise squared distances ----
    for (int p = tid; p < NPAIR; p += NTHREADS) {
        int i = p >> 6, j = p & 63;
        float acc = 0.f;
        #pragma unroll
        for (int d = 0; d < DD; ++d) {
            float df = xs[i*DD+d] - xs[j*DD+d];
            acc += df*df;
        }
        dist2[p]   = acc;
        sortbuf[p] = acc;
    }
    __syncthreads();

    // ---- bitonic sort (ascending) of sortbuf[0..4095] for the median ----
    for (unsigned k = 2; k <= NPAIR; k <<= 1) {
        for (unsigned j = k >> 1; j > 0; j >>= 1) {
            for (unsigned i = tid; i < NPAIR; i += NTHREADS) {
                unsigned ixj = i ^ j;
                if (ixj > i) {
                    float a = sortbuf[i], b = sortbuf[ixj];
                    bool up = ((i & k) == 0);
                    if ((a > b) == up) { sortbuf[i] = b; sortbuf[ixj] = a; }
                }
            }
            __syncthreads();
        }
    }
    if (tid == 0) {
        float med = 0.5f*(sortbuf[NPAIR/2 - 1] + sortbuf[NPAIR/2]);
        denomS = med / logf((float)NP) + 1e-6f;   // h + 1e-6
    }
    __syncthreads();
    const float inv_denom = 1.0f / denomS;

    // ---- main accumulation: 2 particles per 32-lane group ----
    for (int rep = 0; rep < 2; ++rep) {
        int i = grp + rep*32;
        float xi = xs[i*DD + lane];
        float si = sN[i];
        float w  = 0.f;
        for (int j = 0; j < NP; ++j) {
            float d2  = dist2[i*64 + j];          // broadcast read
            float K   = __expf(-d2 * inv_denom);
            float sj  = sN[j];
            float dot = 0.5f*(si + sj - d2);      // x_i . x_j
            float a   = 2.0f * K * inv_denom;
            float b   = K * (-2.0f*dot*inv_denom - (float)(DD-1)) / sj;
            w += K*Ds[j*DD + lane] + a*xi + b*xs[j*DD + lane];
        }
        // project: P(x_i) w = w - x_i (x_i.w)/s_i
        float r = xi * w;
        for (int m = 16; m; m >>= 1) r += __shfl_xor(r, m, 32);
        float pw = w - xi * (r / si);
        // diagonal deriv term, normalize, step, clip
        float g  = (pw - (float)(DD-1)*xi/si) * (1.0f/(float)NP);
        float dx = 0.1f * g;
        dx = fminf(fmaxf(dx, -1000.f), 1000.f);
        out[i*DD + lane] = xi + dx;
    }
}

extern "C" void kernel_launch(void* const* d_in, const int* in_sizes, int n_in,
                              void* d_out, int out_size, void* d_ws, size_t ws_size,
                              hipStream_t stream) {
    const float* particle = (const float*)d_in[0];
    const float* mu       = (const float*)d_in[1];
    float* out            = (float*)d_out;
    hipLaunchKernelGGL(svgd_kernel, dim3(1), dim3(NTHREADS), 0, stream,
                       particle, mu, out);
}

// Round 2
// 26.514 us; speedup vs baseline: 3.2832x; 3.2832x over previous
//
#include <hip/hip_runtime.h>
#include <math.h>

#define NP 64
#define DD 32
#define NTHREADS 1024

__device__ __forceinline__ float readlane_f(float v, int lane) {
    return __int_as_float(__builtin_amdgcn_readlane(__float_as_int(v), lane));
}

__global__ __launch_bounds__(NTHREADS)
void svgd_kernel(const float* __restrict__ particle,
                 const float* __restrict__ mu,
                 float* __restrict__ out) {
    __shared__ float4  xs4[NP*DD/4];     // row-major [j][d] as float4, 8KB
    __shared__ float   xsT[DD*65];       // transposed [d][j], padded stride 65
    __shared__ float4  muS4[DD/4];
    __shared__ float   sN[NP];
    __shared__ float   qv[NP];           // (x_j . mu) / s_j
    __shared__ float   dist2[NP*NP];     // 16KB
    __shared__ unsigned selU[2048];      // upper-tri dist2 bits + pad, 8KB
    __shared__ float2  KEf[NP*NP];       // (K_ij, E_ij) at [j*64+i], 32KB
    __shared__ float   denomS;

    const int tid  = threadIdx.x;
    const int lane = tid & 63;
    const int wv   = tid >> 6;

    // ---------- P0: load inputs, build both layouts ----------
    if (tid < NP*DD/4) {
        float4 v = ((const float4*)particle)[tid];
        xs4[tid] = v;
        int j  = tid >> 3;          // particle
        int d0 = (tid & 7) * 4;     // dim base
        xsT[(d0+0)*65 + j] = v.x;
        xsT[(d0+1)*65 + j] = v.y;
        xsT[(d0+2)*65 + j] = v.z;
        xsT[(d0+3)*65 + j] = v.w;
    }
    if (tid < DD/4) muS4[tid] = ((const float4*)mu)[tid];
    if (tid < 32)  selU[2016 + tid] = 0xFFFFFFFFu;   // pad to 2048
    __syncthreads();

    // ---------- P1: gram-based dist2 (lane = particle j, 4 rows per wave) ----
    float xv[DD];
    #pragma unroll
    for (int d = 0; d < DD; ++d) xv[d] = xsT[d*65 + lane];
    float sj = 0.f;
    #pragma unroll
    for (int d = 0; d < DD; ++d) sj = fmaf(xv[d], xv[d], sj);

    if (wv == 0) {
        sN[lane] = sj;
        const float* muSs = (const float*)muS4;
        float mreg = muSs[lane & 31];
        float mdot = 0.f;
        #pragma unroll
        for (int d = 0; d < DD; ++d) mdot = fmaf(readlane_f(mreg, d), xv[d], mdot);
        qv[lane] = mdot / sj;
    }

    #pragma unroll
    for (int r = 0; r < 4; ++r) {
        int i = wv*4 + r;
        float acc = 0.f;
        #pragma unroll
        for (int d = 0; d < DD; ++d) acc = fmaf(readlane_f(xv[d], i), xv[d], acc);
        float si = readlane_f(sj, i);
        float d2 = si + sj - 2.f*acc;        // exact 0 on diagonal
        dist2[i*64 + lane] = d2;
        if (i < lane) {                      // upper triangle, compact
            int base = i*63 - ((i*(i-1)) >> 1);
            selU[base + lane - i - 1] = __float_as_uint(d2);
        }
    }
    __syncthreads();

    // ---------- P2: wave-0 exact median (ranks 991,992 of 2016) ----------
    if (wv == 0) {
        unsigned vr[32];
        #pragma unroll
        for (int r = 0; r < 32; ++r) vr[r] = selU[r*64 + lane];
        unsigned prefix = 0; int rank = 991;
        for (int bit = 31; bit >= 0; --bit) {
            unsigned bm  = 1u << bit;
            unsigned msk = ~(bm - 1u);       // bits >= bit
            int cnt = 0;
            #pragma unroll
            for (int r = 0; r < 32; ++r)
                cnt += __popcll(__ballot((vr[r] & msk) == prefix));
            if (rank >= cnt) { prefix |= bm; rank -= cnt; }
        }
        // rank-992 value: prefix again if multiplicity covers it, else min of greater
        int cle = 0; unsigned mn = 0xFFFFFFFFu;
        #pragma unroll
        for (int r = 0; r < 32; ++r) {
            unsigned v = vr[r];
            cle += __popcll(__ballot(v <= prefix));
            if (v > prefix && v < mn) mn = v;
        }
        #pragma unroll
        for (int m = 32; m >= 1; m >>= 1) {
            unsigned o = (unsigned)__shfl_xor((int)mn, m, 64);
            mn = (o < mn) ? o : mn;
        }
        unsigned v992 = (cle >= 993) ? prefix : mn;
        if (lane == 0) {
            float med = 0.5f*(__uint_as_float(prefix) + __uint_as_float(v992));
            denomS = med * (1.0f/4.1588830833596715f) + 1e-6f;  // /ln(64) + eps
        }
    }
    __syncthreads();

    // ---------- P3: per-pair (K, E) ----------
    const float invd = 1.0f / denomS;
    #pragma unroll
    for (int t = 0; t < 4; ++t) {
        int p  = tid + t*NTHREADS;
        int jr = p >> 6;                 // summation index j (row)
        int ic = p & 63;                 // output index i (col)
        float d2  = dist2[p];            // symmetric, so [j][i] == [i][j]
        float K   = __expf(-d2 * invd);
        float dot = 0.5f*(sN[ic] + sN[jr] - d2);
        float b   = K * (-2.f*dot*invd - (float)(DD-1)) / sN[jr];
        float E   = b - K * qv[jr];
        KEf[p] = make_float2(K, E);
    }
    __syncthreads();

    // ---------- P4: main accumulation, 512 threads = (i, dim-quad q) ----------
    if (tid < 512) {
        int i = tid >> 3, q = tid & 7;
        float4 xi4 = xs4[i*8 + q];
        float  si  = sN[i];
        float4 w4  = make_float4(0.f,0.f,0.f,0.f);
        float  kacc = 0.f;
        for (int j = 0; j < NP; ++j) {
            float2 KE = KEf[j*64 + i];
            float4 x4 = xs4[j*8 + q];
            w4.x = fmaf(KE.y, x4.x, w4.x);
            w4.y = fmaf(KE.y, x4.y, w4.y);
            w4.z = fmaf(KE.y, x4.z, w4.z);
            w4.w = fmaf(KE.y, x4.w, w4.w);
            kacc += KE.x;
        }
        float4 mu4 = muS4[q];
        float  c2  = 2.f*invd*kacc;
        w4.x += kacc*mu4.x + c2*xi4.x;
        w4.y += kacc*mu4.y + c2*xi4.y;
        w4.z += kacc*mu4.z + c2*xi4.z;
        w4.w += kacc*mu4.w + c2*xi4.w;
        // r = x_i . w  (reduce over the 8 q-lanes)
        float rdot = xi4.x*w4.x + xi4.y*w4.y + xi4.z*w4.z + xi4.w*w4.w;
        rdot += __shfl_xor(rdot, 1, 64);
        rdot += __shfl_xor(rdot, 2, 64);
        rdot += __shfl_xor(rdot, 4, 64);
        float s3 = (rdot + (float)(DD-1)) / si;   // (r + 31)/si
        float4 o4;
        float gx = (w4.x - xi4.x*s3) * (1.f/(float)NP);
        float gy = (w4.y - xi4.y*s3) * (1.f/(float)NP);
        float gz = (w4.z - xi4.z*s3) * (1.f/(float)NP);
        float gw = (w4.w - xi4.w*s3) * (1.f/(float)NP);
        o4.x = xi4.x + fminf(fmaxf(0.1f*gx, -1000.f), 1000.f);
        o4.y = xi4.y + fminf(fmaxf(0.1f*gy, -1000.f), 1000.f);
        o4.z = xi4.z + fminf(fmaxf(0.1f*gz, -1000.f), 1000.f);
        o4.w = xi4.w + fminf(fmaxf(0.1f*gw, -1000.f), 1000.f);
        ((float4*)out)[tid] = o4;
    }
}

extern "C" void kernel_launch(void* const* d_in, const int* in_sizes, int n_in,
                              void* d_out, int out_size, void* d_ws, size_t ws_size,
                              hipStream_t stream) {
    const float* particle = (const float*)d_in[0];
    const float* mu       = (const float*)d_in[1];
    float* outp           = (float*)d_out;
    hipLaunchKernelGGL(svgd_kernel, dim3(1), dim3(NTHREADS), 0, stream,
                       particle, mu, outp);
}

// Round 3
// 24.258 us; speedup vs baseline: 3.5887x; 1.0930x over previous
//
#include <hip/hip_runtime.h>
#include <math.h>

#define NP 64
#define DD 32
#define NTHREADS 1024

__device__ __forceinline__ float readlane_f(float v, int lane) {
    return __int_as_float(__builtin_amdgcn_readlane(__float_as_int(v), lane));
}

__global__ __launch_bounds__(NTHREADS)
void svgd_kernel(const float* __restrict__ particle,
                 const float* __restrict__ mu,
                 float* __restrict__ out) {
    __shared__ float4  xs4[NP*DD/4];     // [j][d/4] row-major, 8KB
    __shared__ float   xsT[DD*65];       // [d][j] padded, 8.3KB
    __shared__ float4  muS4[DD/4];
    __shared__ float   sNarr[NP];
    __shared__ float4  jinfo[NP];        // (sj, 1/sj, -qv_j, 0), 1KB
    __shared__ float   dist2[NP*NP];     // 16KB
    __shared__ unsigned selU[2048];      // upper-tri bits + pad, 8KB
    __shared__ float2  KEf[NP*NP];       // (K,E) at [j*64+i], 32KB
    __shared__ float4  wpartL[512];      // h=1 partial w, 8KB
    __shared__ float   kpartL[512];      // h=1 partial kacc, 2KB
    __shared__ float   invdS;

    const int tid  = threadIdx.x;
    const int lane = tid & 63;
    const int wv   = tid >> 6;

    // ---------- P0: load inputs, build both layouts ----------
    if (tid < NP*DD/4) {
        float4 v = ((const float4*)particle)[tid];
        xs4[tid] = v;
        int j  = tid >> 3;
        int d0 = (tid & 7) * 4;
        xsT[(d0+0)*65 + j] = v.x;
        xsT[(d0+1)*65 + j] = v.y;
        xsT[(d0+2)*65 + j] = v.z;
        xsT[(d0+3)*65 + j] = v.w;
    }
    if (tid < DD/4) muS4[tid] = ((const float4*)mu)[tid];
    if (tid < 32)  selU[2016 + tid] = 0xFFFFFFFFu;
    __syncthreads();

    // ---------- P1: norms, jinfo (wave 0) + gram dist2 (all waves) ----------
    float xv[DD];
    #pragma unroll
    for (int d = 0; d < DD; ++d) xv[d] = xsT[d*65 + lane];
    float sj = 0.f;
    #pragma unroll
    for (int d = 0; d < DD; ++d) sj = fmaf(xv[d], xv[d], sj);

    if (wv == 0) {
        sNarr[lane] = sj;
        const float* muSs = (const float*)muS4;
        float mreg = muSs[lane & 31];
        float mdot = 0.f;
        #pragma unroll
        for (int d = 0; d < DD; ++d) mdot = fmaf(readlane_f(mreg, d), xv[d], mdot);
        float inv_sj = 1.0f / sj;
        jinfo[lane] = make_float4(sj, inv_sj, -mdot*inv_sj, 0.f);
    }

    #pragma unroll
    for (int r = 0; r < 4; ++r) {
        int i = wv*4 + r;
        float acc = 0.f;
        #pragma unroll
        for (int d = 0; d < DD; ++d) acc = fmaf(readlane_f(xv[d], i), xv[d], acc);
        float si = readlane_f(sj, i);
        float d2 = si + sj - 2.f*acc;
        dist2[i*64 + lane] = d2;
        if (i < lane) {
            int base = i*63 - ((i*(i-1)) >> 1);
            selU[base + lane - i - 1] = __float_as_uint(d2);
        }
    }
    __syncthreads();

    // ---------- P2: wave-0 median, bit-descent on bits 30..8 ----------
    if (wv == 0) {
        unsigned vr[32];
        #pragma unroll
        for (int r = 0; r < 32; ++r) vr[r] = selU[r*64 + lane];
        unsigned prefix = 0; int rank = 991;
        for (int bit = 30; bit >= 8; --bit) {
            unsigned bm  = 1u << bit;
            unsigned msk = ~(bm - 1u);
            int cnt = 0;
            #pragma unroll
            for (int r = 0; r < 32; ++r)
                cnt += __popcll(__ballot((vr[r] & msk) == prefix));
            if (rank >= cnt) { prefix |= bm; rank -= cnt; }
        }
        int cle = 0; unsigned mn = 0xFFFFFFFFu;
        #pragma unroll
        for (int r = 0; r < 32; ++r) {
            unsigned tv = vr[r] & 0xFFFFFF00u;
            cle += __popcll(__ballot(tv <= prefix));
            if (tv > prefix && tv < mn) mn = tv;
        }
        #pragma unroll
        for (int m = 32; m >= 1; m >>= 1) {
            unsigned o = (unsigned)__shfl_xor((int)mn, m, 64);
            mn = (o < mn) ? o : mn;
        }
        unsigned v992 = (cle >= 993) ? prefix : mn;
        if (lane == 0) {
            float med = 0.5f*(__uint_as_float(prefix) + __uint_as_float(v992));
            float denom = med * (1.0f/4.1588830833596715f) + 1e-6f;
            invdS = 1.0f / denom;
        }
    }
    __syncthreads();

    // ---------- P3: per-pair (K, E) ----------
    const float invd = invdS;
    const float si_l = sNarr[lane];
    #pragma unroll
    for (int t = 0; t < 4; ++t) {
        int p  = tid + t*NTHREADS;
        int jr = (tid >> 6) + t*16;          // wave-uniform summation index
        float4 ji = jinfo[jr];               // (sj, inv_sj, -qv, 0) broadcast
        float d2  = dist2[p];
        float K   = __expf(-d2 * invd);
        float u   = d2 - si_l - ji.x;
        float t1  = fmaf(invd, u, -(float)(DD-1));
        float E   = K * fmaf(t1, ji.y, ji.z);
        KEf[p] = make_float2(K, E);
    }
    __syncthreads();

    // ---------- P4: accumulation split over j-halves, all 1024 threads ----
    {
        int h = tid >> 9;                    // j-half
        int r = tid & 511;
        int i = r >> 3, q = r & 7;
        float4 w4  = make_float4(0.f,0.f,0.f,0.f);
        float  kacc = 0.f;
        int j0 = h*32;
        #pragma unroll 8
        for (int jj = 0; jj < 32; ++jj) {
            int j = j0 + jj;
            float2 KE = KEf[j*64 + i];
            float4 x4 = xs4[j*8 + q];
            w4.x = fmaf(KE.y, x4.x, w4.x);
            w4.y = fmaf(KE.y, x4.y, w4.y);
            w4.z = fmaf(KE.y, x4.z, w4.z);
            w4.w = fmaf(KE.y, x4.w, w4.w);
            kacc += KE.x;
        }
        if (h == 1) { wpartL[r] = w4; kpartL[r] = kacc; }
        __syncthreads();
        if (h == 0) {
            float4 wp = wpartL[r];
            w4.x += wp.x; w4.y += wp.y; w4.z += wp.z; w4.w += wp.w;
            kacc += kpartL[r];

            float4 xi4 = xs4[i*8 + q];
            float4 ji  = jinfo[i];           // .y = 1/si
            float4 mu4 = muS4[q];
            float  c2  = 2.f*invd*kacc;
            w4.x += kacc*mu4.x + c2*xi4.x;
            w4.y += kacc*mu4.y + c2*xi4.y;
            w4.z += kacc*mu4.z + c2*xi4.z;
            w4.w += kacc*mu4.w + c2*xi4.w;
            float rdot = xi4.x*w4.x + xi4.y*w4.y + xi4.z*w4.z + xi4.w*w4.w;
            rdot += __shfl_xor(rdot, 1, 64);
            rdot += __shfl_xor(rdot, 2, 64);
            rdot += __shfl_xor(rdot, 4, 64);
            float s3 = (rdot + (float)(DD-1)) * ji.y;
            float gx = (w4.x - xi4.x*s3) * (1.f/(float)NP);
            float gy = (w4.y - xi4.y*s3) * (1.f/(float)NP);
            float gz = (w4.z - xi4.z*s3) * (1.f/(float)NP);
            float gw = (w4.w - xi4.w*s3) * (1.f/(float)NP);
            float4 o4;
            o4.x = xi4.x + fminf(fmaxf(0.1f*gx, -1000.f), 1000.f);
            o4.y = xi4.y + fminf(fmaxf(0.1f*gy, -1000.f), 1000.f);
            o4.z = xi4.z + fminf(fmaxf(0.1f*gz, -1000.f), 1000.f);
            o4.w = xi4.w + fminf(fmaxf(0.1f*gw, -1000.f), 1000.f);
            ((float4*)out)[r] = o4;
        }
    }
}

extern "C" void kernel_launch(void* const* d_in, const int* in_sizes, int n_in,
                              void* d_out, int out_size, void* d_ws, size_t ws_size,
                              hipStream_t stream) {
    const float* particle = (const float*)d_in[0];
    const float* mu       = (const float*)d_in[1];
    float* outp           = (float*)d_out;
    hipLaunchKernelGGL(svgd_kernel, dim3(1), dim3(NTHREADS), 0, stream,
                       particle, mu, outp);
}

// Round 4
// 20.776 us; speedup vs baseline: 4.1899x; 1.1676x over previous
//
#include <hip/hip_runtime.h>
#include <math.h>

#define NP 64
#define DD 32
#define NTHREADS 1024
#define NB 8            // blocks; each owns 8 output particles

__device__ __forceinline__ float readlane_f(float v, int lane) {
    return __int_as_float(__builtin_amdgcn_readlane(__float_as_int(v), lane));
}

__global__ __launch_bounds__(NTHREADS)
void svgd_kernel(const float* __restrict__ particle,
                 const float* __restrict__ mu,
                 float* __restrict__ out) {
    __shared__ float4  xs4[NP*DD/4];     // [j][d/4], 8KB
    __shared__ float   xsT[DD*65];       // [d][j] padded
    __shared__ float4  muS4[DD/4];
    __shared__ float   sNarr[NP];
    __shared__ float4  jinfo[NP];        // (sj, 1/sj, -qv_j, 0)
    __shared__ float   dist2[NP*NP];     // 16KB
    __shared__ unsigned selU[2048];      // upper-tri bits + pad
    __shared__ float2  Ecol[NP*8];       // (K,E) for this block's 8 i's, 4KB
    __shared__ float4  wpart[3*64];      // h=1..3 partial w
    __shared__ float   kpart[3*64];
    __shared__ float   invdS;

    const int tid  = threadIdx.x;
    const int lane = tid & 63;
    const int wv   = tid >> 6;
    const int i0   = blockIdx.x * 8;     // this block's output particles

    // ---------- P0: load inputs, build both layouts ----------
    if (tid < NP*DD/4) {
        float4 v = ((const float4*)particle)[tid];
        xs4[tid] = v;
        int j  = tid >> 3;
        int d0 = (tid & 7) * 4;
        xsT[(d0+0)*65 + j] = v.x;
        xsT[(d0+1)*65 + j] = v.y;
        xsT[(d0+2)*65 + j] = v.z;
        xsT[(d0+3)*65 + j] = v.w;
    }
    if (tid < DD/4) muS4[tid] = ((const float4*)mu)[tid];
    if (tid < 32)  selU[2016 + tid] = 0xFFFFFFFFu;
    __syncthreads();

    // ---------- P1: norms + jinfo (wave 0), full gram dist2 (all waves) ----
    float xv[DD];
    #pragma unroll
    for (int d = 0; d < DD; ++d) xv[d] = xsT[d*65 + lane];
    float sj = 0.f;
    #pragma unroll
    for (int d = 0; d < DD; ++d) sj = fmaf(xv[d], xv[d], sj);

    if (wv == 0) {
        sNarr[lane] = sj;
        const float* muSs = (const float*)muS4;
        float mreg = muSs[lane & 31];
        float mdot = 0.f;
        #pragma unroll
        for (int d = 0; d < DD; ++d) mdot = fmaf(readlane_f(mreg, d), xv[d], mdot);
        float inv_sj = 1.0f / sj;
        jinfo[lane] = make_float4(sj, inv_sj, -mdot*inv_sj, 0.f);
    }

    #pragma unroll
    for (int r = 0; r < 4; ++r) {
        int i = wv*4 + r;
        float acc = 0.f;
        #pragma unroll
        for (int d = 0; d < DD; ++d) acc = fmaf(readlane_f(xv[d], i), xv[d], acc);
        float si = readlane_f(sj, i);
        float d2 = si + sj - 2.f*acc;
        dist2[i*64 + lane] = d2;
        if (i < lane) {
            int base = i*63 - ((i*(i-1)) >> 1);
            selU[base + lane - i - 1] = __float_as_uint(d2);
        }
    }
    __syncthreads();

    // ---------- P2: wave-0 exact median (bit-descent, bits 30..8) ----------
    if (wv == 0) {
        unsigned vr[32];
        #pragma unroll
        for (int r = 0; r < 32; ++r) vr[r] = selU[r*64 + lane];
        unsigned prefix = 0; int rank = 991;
        for (int bit = 30; bit >= 8; --bit) {
            unsigned bm  = 1u << bit;
            unsigned msk = ~(bm - 1u);
            int cnt = 0;
            #pragma unroll
            for (int r = 0; r < 32; ++r)
                cnt += __popcll(__ballot((vr[r] & msk) == prefix));
            if (rank >= cnt) { prefix |= bm; rank -= cnt; }
        }
        int cle = 0; unsigned mn = 0xFFFFFFFFu;
        #pragma unroll
        for (int r = 0; r < 32; ++r) {
            unsigned tv = vr[r] & 0xFFFFFF00u;
            cle += __popcll(__ballot(tv <= prefix));
            if (tv > prefix && tv < mn) mn = tv;
        }
        #pragma unroll
        for (int m = 32; m >= 1; m >>= 1) {
            unsigned o = (unsigned)__shfl_xor((int)mn, m, 64);
            mn = (o < mn) ? o : mn;
        }
        unsigned v992 = (cle >= 993) ? prefix : mn;
        if (lane == 0) {
            float med = 0.5f*(__uint_as_float(prefix) + __uint_as_float(v992));
            float denom = med * (1.0f/4.1588830833596715f) + 1e-6f;
            invdS = 1.0f / denom;
        }
    }
    __syncthreads();

    // ---------- P3: (K,E) for this block's 8 columns only ----------
    const float invd = invdS;
    if (tid < 512) {
        int j  = tid >> 3;
        int il = tid & 7;
        int i  = i0 + il;
        float4 ji = jinfo[j];
        float d2  = dist2[j*64 + i];
        float K   = __expf(-d2 * invd);
        float u   = d2 - sNarr[i] - ji.x;
        float t1  = fmaf(invd, u, -(float)(DD-1));
        float E   = K * fmaf(t1, ji.y, ji.z);
        Ecol[j*8 + il] = make_float2(K, E);
    }
    __syncthreads();

    // ---------- P4: accumulate over j in 4 groups of 16, then combine ------
    {
        float4 w4 = make_float4(0.f,0.f,0.f,0.f);
        float  kacc = 0.f;
        if (tid < 256) {
            int h  = tid >> 6;           // j-group (= wave index)
            int il = (tid >> 3) & 7;
            int q  = tid & 7;
            #pragma unroll
            for (int jj = 0; jj < 16; ++jj) {
                int j = h*16 + jj;
                float2 KE = Ecol[j*8 + il];
                float4 x4 = xs4[j*8 + q];
                w4.x = fmaf(KE.y, x4.x, w4.x);
                w4.y = fmaf(KE.y, x4.y, w4.y);
                w4.z = fmaf(KE.y, x4.z, w4.z);
                w4.w = fmaf(KE.y, x4.w, w4.w);
                kacc += KE.x;
            }
            if (h > 0) {
                wpart[(h-1)*64 + (tid & 63)] = w4;
                kpart[(h-1)*64 + (tid & 63)] = kacc;
            }
        }
        __syncthreads();
        if (tid < 64) {                  // h==0 wave finishes
            #pragma unroll
            for (int p = 0; p < 3; ++p) {
                float4 wp = wpart[p*64 + tid];
                w4.x += wp.x; w4.y += wp.y; w4.z += wp.z; w4.w += wp.w;
                kacc += kpart[p*64 + tid];
            }
            int il = tid >> 3, q = tid & 7;
            int i  = i0 + il;
            float4 xi4 = xs4[i*8 + q];
            float4 ji  = jinfo[i];       // .y = 1/si
            float4 mu4 = muS4[q];
            float  c2  = 2.f*invd*kacc;
            w4.x += kacc*mu4.x + c2*xi4.x;
            w4.y += kacc*mu4.y + c2*xi4.y;
            w4.z += kacc*mu4.z + c2*xi4.z;
            w4.w += kacc*mu4.w + c2*xi4.w;
            float rdot = xi4.x*w4.x + xi4.y*w4.y + xi4.z*w4.z + xi4.w*w4.w;
            rdot += __shfl_xor(rdot, 1, 64);
            rdot += __shfl_xor(rdot, 2, 64);
            rdot += __shfl_xor(rdot, 4, 64);
            float s3 = (rdot + (float)(DD-1)) * ji.y;
            float gx = (w4.x - xi4.x*s3) * (1.f/(float)NP);
            float gy = (w4.y - xi4.y*s3) * (1.f/(float)NP);
            float gz = (w4.z - xi4.z*s3) * (1.f/(float)NP);
            float gw = (w4.w - xi4.w*s3) * (1.f/(float)NP);
            float4 o4;
            o4.x = xi4.x + fminf(fmaxf(0.1f*gx, -1000.f), 1000.f);
            o4.y = xi4.y + fminf(fmaxf(0.1f*gy, -1000.f), 1000.f);
            o4.z = xi4.z + fminf(fmaxf(0.1f*gz, -1000.f), 1000.f);
            o4.w = xi4.w + fminf(fmaxf(0.1f*gw, -1000.f), 1000.f);
            ((float4*)out)[i*8 + q] = o4;
        }
    }
}

extern "C" void kernel_launch(void* const* d_in, const int* in_sizes, int n_in,
                              void* d_out, int out_size, void* d_ws, size_t ws_size,
                              hipStream_t stream) {
    const float* particle = (const float*)d_in[0];
    const float* mu       = (const float*)d_in[1];
    float* outp           = (float*)d_out;
    hipLaunchKernelGGL(svgd_kernel, dim3(NB), dim3(NTHREADS), 0, stream,
                       particle, mu, outp);
}

// Round 5
// 20.108 us; speedup vs baseline: 4.3292x; 1.0332x over previous
//
#include <hip/hip_runtime.h>
#include <math.h>

#define NP 64
#define DD 32
#define NTHREADS 1024
#define NB 8            // blocks; each owns 8 output particles

__device__ __forceinline__ float readlane_f(float v, int lane) {
    return __int_as_float(__builtin_amdgcn_readlane(__float_as_int(v), lane));
}

__global__ __launch_bounds__(NTHREADS)
void svgd_kernel(const float* __restrict__ particle,
                 const float* __restrict__ mu,
                 float* __restrict__ out) {
    __shared__ float   sNarr[NP];
    __shared__ float4  jinfo[NP];        // (sj, 1/sj, -qv_j, 0)
    __shared__ float   dist2[NP*NP];     // 16KB
    __shared__ unsigned selU[2048];      // upper-tri bits + pad
    __shared__ float2  Ecol[NP*8];       // (K,E) for this block's 8 i's
    __shared__ float4  wpart[3*64];
    __shared__ float   kpart[3*64];
    __shared__ float   invdS;

    const int tid  = threadIdx.x;
    const int lane = tid & 63;
    const int wv   = tid >> 6;
    const int i0   = blockIdx.x * 8;

    if (tid < 32) selU[2016 + tid] = 0xFFFFFFFFu;

    // ---------- P1: particle row straight from global into registers -------
    float4 xq[8];
    #pragma unroll
    for (int k = 0; k < 8; ++k) xq[k] = ((const float4*)particle)[lane*8 + k];
    float xv[DD];
    #pragma unroll
    for (int k = 0; k < 8; ++k) {
        xv[4*k+0] = xq[k].x; xv[4*k+1] = xq[k].y;
        xv[4*k+2] = xq[k].z; xv[4*k+3] = xq[k].w;
    }
    float sj = 0.f;
    #pragma unroll
    for (int d = 0; d < DD; ++d) sj = fmaf(xv[d], xv[d], sj);

    if (wv == 0) {
        sNarr[lane] = sj;
        float mreg = mu[lane & 31];
        float mdot = 0.f;
        #pragma unroll
        for (int d = 0; d < DD; ++d) mdot = fmaf(readlane_f(mreg, d), xv[d], mdot);
        float inv_sj = 1.0f / sj;
        jinfo[lane] = make_float4(sj, inv_sj, -mdot*inv_sj, 0.f);
    }

    #pragma unroll
    for (int r = 0; r < 4; ++r) {
        int i = wv*4 + r;
        float acc = 0.f;
        #pragma unroll
        for (int d = 0; d < DD; ++d) acc = fmaf(readlane_f(xv[d], i), xv[d], acc);
        float si = readlane_f(sj, i);
        float d2 = si + sj - 2.f*acc;
        dist2[i*64 + lane] = d2;
        if (i < lane) {
            int base = i*63 - ((i*(i-1)) >> 1);
            selU[base + lane - i - 1] = __float_as_uint(d2);
        }
    }
    __syncthreads();

    // ---------- P2: wave-0 exact median, adaptive-start bit-descent --------
    if (wv == 0) {
        unsigned vr[32];
        #pragma unroll
        for (int r = 0; r < 32; ++r) vr[r] = selU[r*64 + lane];
        // min/max over real values (exclude the 32 pad entries: r==31, lane>=32)
        unsigned mx = 0u, mnv = 0xFFFFFFFFu;
        #pragma unroll
        for (int r = 0; r < 32; ++r) {
            unsigned v = vr[r];
            unsigned vm = (r == 31 && lane >= 32) ? 0u          : v;
            unsigned vn = (r == 31 && lane >= 32) ? 0xFFFFFFFFu : v;
            mx  = vm > mx  ? vm : mx;
            mnv = vn < mnv ? vn : mnv;
        }
        #pragma unroll
        for (int m = 32; m >= 1; m >>= 1) {
            unsigned ox = (unsigned)__shfl_xor((int)mx,  m, 64);
            unsigned on = (unsigned)__shfl_xor((int)mnv, m, 64);
            mx  = ox > mx  ? ox : mx;
            mnv = on < mnv ? on : mnv;
        }
        unsigned diff = mnv ^ mx;
        int startbit = 31 - __clz((int)(diff | 1u));
        if (startbit < 12) startbit = 12;        // still do one refinement iter
        unsigned prefix = mnv & ~((1u << (startbit + 1)) - 1u);  // shared bits
        int rank = 991;
        for (int bit = startbit; bit >= 12; --bit) {
            unsigned bm  = 1u << bit;
            unsigned msk = ~(bm - 1u);
            int cnt = 0;
            #pragma unroll
            for (int r = 0; r < 32; ++r)
                cnt += __popcll(__ballot((vr[r] & msk) == prefix));
            if (rank >= cnt) { prefix |= bm; rank -= cnt; }
        }
        // rank-992 value (bits >= 12)
        int cle = 0; unsigned mn2 = 0xFFFFFFFFu;
        #pragma unroll
        for (int r = 0; r < 32; ++r) {
            unsigned tv = vr[r] & 0xFFFFF000u;
            cle += __popcll(__ballot(tv <= prefix));
            if (tv > prefix && tv < mn2) mn2 = tv;
        }
        #pragma unroll
        for (int m = 32; m >= 1; m >>= 1) {
            unsigned o = (unsigned)__shfl_xor((int)mn2, m, 64);
            mn2 = (o < mn2) ? o : mn2;
        }
        unsigned v992 = (cle >= 993) ? prefix : mn2;
        if (lane == 0) {
            float med = 0.5f*(__uint_as_float(prefix) + __uint_as_float(v992));
            float denom = med * (1.0f/4.1588830833596715f) + 1e-6f;  // /ln(64)+eps
            invdS = 1.0f / denom;
        }
    }
    __syncthreads();

    // ---------- P3: (K,E) for this block's 8 columns ----------
    const float invd = invdS;
    if (tid < 512) {
        int j  = tid >> 3;
        int il = tid & 7;
        int i  = i0 + il;
        float4 ji = jinfo[j];
        float d2  = dist2[j*64 + i];
        float K   = __expf(-d2 * invd);
        float u   = d2 - sNarr[i] - ji.x;
        float t1  = fmaf(invd, u, -(float)(DD-1));
        float E   = K * fmaf(t1, ji.y, ji.z);
        Ecol[j*8 + il] = make_float2(K, E);
    }
    __syncthreads();

    // ---------- P4: accumulate over j in 4 groups of 16, then combine ------
    {
        float4 w4 = make_float4(0.f,0.f,0.f,0.f);
        float  kacc = 0.f;
        if (tid < 256) {
            int h  = tid >> 6;
            int il = (tid >> 3) & 7;
            int q  = tid & 7;
            #pragma unroll
            for (int jj = 0; jj < 16; ++jj) {
                int j = h*16 + jj;
                float2 KE = Ecol[j*8 + il];
                float4 x4 = ((const float4*)particle)[j*8 + q];
                w4.x = fmaf(KE.y, x4.x, w4.x);
                w4.y = fmaf(KE.y, x4.y, w4.y);
                w4.z = fmaf(KE.y, x4.z, w4.z);
                w4.w = fmaf(KE.y, x4.w, w4.w);
                kacc += KE.x;
            }
            if (h > 0) {
                wpart[(h-1)*64 + (tid & 63)] = w4;
                kpart[(h-1)*64 + (tid & 63)] = kacc;
            }
        }
        __syncthreads();
        if (tid < 64) {
            #pragma unroll
            for (int p = 0; p < 3; ++p) {
                float4 wp = wpart[p*64 + tid];
                w4.x += wp.x; w4.y += wp.y; w4.z += wp.z; w4.w += wp.w;
                kacc += kpart[p*64 + tid];
            }
            int il = tid >> 3, q = tid & 7;
            int i  = i0 + il;
            float4 xi4 = ((const float4*)particle)[i*8 + q];
            float4 mu4 = ((const float4*)mu)[q];
            float4 ji  = jinfo[i];       // .y = 1/si
            float  c2  = 2.f*invd*kacc;
            w4.x += kacc*mu4.x + c2*xi4.x;
            w4.y += kacc*mu4.y + c2*xi4.y;
            w4.z += kacc*mu4.z + c2*xi4.z;
            w4.w += kacc*mu4.w + c2*xi4.w;
            float rdot = xi4.x*w4.x + xi4.y*w4.y + xi4.z*w4.z + xi4.w*w4.w;
            rdot += __shfl_xor(rdot, 1, 64);
            rdot += __shfl_xor(rdot, 2, 64);
            rdot += __shfl_xor(rdot, 4, 64);
            float s3 = (rdot + (float)(DD-1)) * ji.y;
            float gx = (w4.x - xi4.x*s3) * (1.f/(float)NP);
            float gy = (w4.y - xi4.y*s3) * (1.f/(float)NP);
            float gz = (w4.z - xi4.z*s3) * (1.f/(float)NP);
            float gw = (w4.w - xi4.w*s3) * (1.f/(float)NP);
            float4 o4;
            o4.x = xi4.x + fminf(fmaxf(0.1f*gx, -1000.f), 1000.f);
            o4.y = xi4.y + fminf(fmaxf(0.1f*gy, -1000.f), 1000.f);
            o4.z = xi4.z + fminf(fmaxf(0.1f*gz, -1000.f), 1000.f);
            o4.w = xi4.w + fminf(fmaxf(0.1f*gw, -1000.f), 1000.f);
            ((float4*)out)[i*8 + q] = o4;
        }
    }
}

extern "C" void kernel_launch(void* const* d_in, const int* in_sizes, int n_in,
                              void* d_out, int out_size, void* d_ws, size_t ws_size,
                              hipStream_t stream) {
    const float* particle = (const float*)d_in[0];
    const float* mu       = (const float*)d_in[1];
    float* outp           = (float*)d_out;
    hipLaunchKernelGGL(svgd_kernel, dim3(NB), dim3(NTHREADS), 0, stream,
                       particle, mu, outp);
}

// Round 6
// 19.088 us; speedup vs baseline: 4.5605x; 1.0534x over previous
//
#include <hip/hip_runtime.h>
#include <math.h>

#define NP 64
#define DD 32
#define NTHREADS 1024
#define NB 8            // blocks; each owns 8 output particles

__device__ __forceinline__ float readlane_f(float v, int lane) {
    return __int_as_float(__builtin_amdgcn_readlane(__float_as_int(v), lane));
}

__global__ __launch_bounds__(NTHREADS)
void svgd_kernel(const float* __restrict__ particle,
                 const float* __restrict__ mu,
                 float* __restrict__ out) {
    __shared__ float   sNarr[NP];
    __shared__ float4  jinfo[NP];        // (sj, 1/sj, -qv_j, 0)
    __shared__ float   dist2[NP*NP];     // 16KB
    __shared__ unsigned selU[2048];      // upper-tri bits + pad
    __shared__ uint2   wmm[16];          // per-wave (min,max) of tri bits
    __shared__ float4  wpart[3*64];
    __shared__ float   kpart[3*64];
    __shared__ float   invdS;

    const int tid  = threadIdx.x;
    const int lane = tid & 63;
    const int wv   = tid >> 6;
    const int i0   = blockIdx.x * 8;

    if (tid < 32) selU[2016 + tid] = 0xFFFFFFFFu;

    // ---------- P1: rows from global, norms, dist2, per-wave min/max -------
    float4 xq[8];
    #pragma unroll
    for (int k = 0; k < 8; ++k) xq[k] = ((const float4*)particle)[lane*8 + k];
    float xv[DD];
    #pragma unroll
    for (int k = 0; k < 8; ++k) {
        xv[4*k+0] = xq[k].x; xv[4*k+1] = xq[k].y;
        xv[4*k+2] = xq[k].z; xv[4*k+3] = xq[k].w;
    }
    float sj = 0.f;
    #pragma unroll
    for (int d = 0; d < DD; ++d) sj = fmaf(xv[d], xv[d], sj);

    if (wv == 0) {
        sNarr[lane] = sj;
        float mreg = mu[lane & 31];
        float mdot = 0.f;
        #pragma unroll
        for (int d = 0; d < DD; ++d) mdot = fmaf(readlane_f(mreg, d), xv[d], mdot);
        float inv_sj = 1.0f / sj;
        jinfo[lane] = make_float4(sj, inv_sj, -mdot*inv_sj, 0.f);
    }

    unsigned tmn = 0xFFFFFFFFu, tmx = 0u;
    #pragma unroll
    for (int r = 0; r < 4; ++r) {
        int i = wv*4 + r;
        float acc = 0.f;
        #pragma unroll
        for (int d = 0; d < DD; ++d) acc = fmaf(readlane_f(xv[d], i), xv[d], acc);
        float si = readlane_f(sj, i);
        float d2 = si + sj - 2.f*acc;
        dist2[i*64 + lane] = d2;
        if (i < lane) {
            int base = i*63 - ((i*(i-1)) >> 1);
            unsigned ub = __float_as_uint(d2);
            selU[base + lane - i - 1] = ub;
            tmn = ub < tmn ? ub : tmn;
            tmx = ub > tmx ? ub : tmx;
        }
    }
    #pragma unroll
    for (int m = 32; m >= 1; m >>= 1) {
        unsigned on = (unsigned)__shfl_xor((int)tmn, m, 64);
        unsigned ox = (unsigned)__shfl_xor((int)tmx, m, 64);
        tmn = on < tmn ? on : tmn;
        tmx = ox > tmx ? ox : tmx;
    }
    if (lane == 0) wmm[wv] = make_uint2(tmn, tmx);
    __syncthreads();

    // ---------- P2: wave-0 exact median, adaptive bit-descent to bit 15 ----
    if (wv == 0) {
        unsigned vr[32];
        #pragma unroll
        for (int r = 0; r < 32; ++r) vr[r] = selU[r*64 + lane];
        uint2 wm = wmm[lane & 15];
        unsigned mnv = wm.x, mx = wm.y;
        #pragma unroll
        for (int m = 8; m >= 1; m >>= 1) {
            unsigned on = (unsigned)__shfl_xor((int)mnv, m, 64);
            unsigned ox = (unsigned)__shfl_xor((int)mx,  m, 64);
            mnv = on < mnv ? on : mnv;
            mx  = ox > mx  ? ox : mx;
        }
        unsigned diff = mnv ^ mx;
        int startbit = 31 - __clz((int)(diff | 1u));
        if (startbit < 15) startbit = 15;
        unsigned prefix = mnv & ~((2u << startbit) - 1u);   // shared high bits
        int rank = 991;
        for (int bit = startbit; bit >= 15; --bit) {
            unsigned bm  = 1u << bit;
            unsigned msk = ~(bm - 1u);
            int cnt = 0;
            #pragma unroll
            for (int r = 0; r < 32; ++r)
                cnt += __popcll(__ballot((vr[r] & msk) == prefix));
            if (rank >= cnt) { prefix |= bm; rank -= cnt; }
        }
        // rank-992 value at bit-15 truncation
        int cle = 0; unsigned mn2 = 0xFFFFFFFFu;
        #pragma unroll
        for (int r = 0; r < 32; ++r) {
            unsigned tv = vr[r] & 0xFFFF8000u;
            cle += __popcll(__ballot(tv <= prefix));
            if (tv > prefix && tv < mn2) mn2 = tv;
        }
        #pragma unroll
        for (int m = 32; m >= 1; m >>= 1) {
            unsigned o = (unsigned)__shfl_xor((int)mn2, m, 64);
            mn2 = (o < mn2) ? o : mn2;
        }
        unsigned v992 = (cle >= 993) ? prefix : mn2;
        if (lane == 0) {
            float med = 0.5f*(__uint_as_float(prefix) + __uint_as_float(v992));
            float denom = med * (1.0f/4.1588830833596715f) + 1e-6f;  // /ln(64)+eps
            invdS = 1.0f / denom;
        }
    }
    __syncthreads();

    // ---------- P4: fused (K,E) + accumulation, 256 threads ----------------
    {
        const float invd = invdS;
        float4 w4 = make_float4(0.f,0.f,0.f,0.f);
        float  kacc = 0.f;
        if (tid < 256) {
            int h  = tid >> 6;
            int il = (tid >> 3) & 7;
            int q  = tid & 7;
            int i  = i0 + il;
            float si = sNarr[i];
            float4 xr[16];
            #pragma unroll
            for (int jj = 0; jj < 16; ++jj)
                xr[jj] = ((const float4*)particle)[(h*16 + jj)*8 + q];
            #pragma unroll
            for (int jj = 0; jj < 16; ++jj) {
                int j = h*16 + jj;
                float4 ji = jinfo[j];
                float d2  = dist2[j*64 + i];
                float K   = __expf(-d2 * invd);
                float u   = d2 - si - ji.x;
                float t1  = fmaf(invd, u, -(float)(DD-1));
                float E   = K * fmaf(t1, ji.y, ji.z);
                float4 x4 = xr[jj];
                w4.x = fmaf(E, x4.x, w4.x);
                w4.y = fmaf(E, x4.y, w4.y);
                w4.z = fmaf(E, x4.z, w4.z);
                w4.w = fmaf(E, x4.w, w4.w);
                kacc += K;
            }
            if (h > 0) {
                wpart[(h-1)*64 + (tid & 63)] = w4;
                kpart[(h-1)*64 + (tid & 63)] = kacc;
            }
        }
        __syncthreads();
        if (tid < 64) {
            #pragma unroll
            for (int p = 0; p < 3; ++p) {
                float4 wp = wpart[p*64 + tid];
                w4.x += wp.x; w4.y += wp.y; w4.z += wp.z; w4.w += wp.w;
                kacc += kpart[p*64 + tid];
            }
            int il = tid >> 3, q = tid & 7;
            int i  = i0 + il;
            float4 xi4 = ((const float4*)particle)[i*8 + q];
            float4 mu4 = ((const float4*)mu)[q];
            float4 ji  = jinfo[i];       // .y = 1/si
            float  c2  = 2.f*invd*kacc;
            w4.x += kacc*mu4.x + c2*xi4.x;
            w4.y += kacc*mu4.y + c2*xi4.y;
            w4.z += kacc*mu4.z + c2*xi4.z;
            w4.w += kacc*mu4.w + c2*xi4.w;
            float rdot = xi4.x*w4.x + xi4.y*w4.y + xi4.z*w4.z + xi4.w*w4.w;
            rdot += __shfl_xor(rdot, 1, 64);
            rdot += __shfl_xor(rdot, 2, 64);
            rdot += __shfl_xor(rdot, 4, 64);
            float s3 = (rdot + (float)(DD-1)) * ji.y;
            float gx = (w4.x - xi4.x*s3) * (1.f/(float)NP);
            float gy = (w4.y - xi4.y*s3) * (1.f/(float)NP);
            float gz = (w4.z - xi4.z*s3) * (1.f/(float)NP);
            float gw = (w4.w - xi4.w*s3) * (1.f/(float)NP);
            float4 o4;
            o4.x = xi4.x + fminf(fmaxf(0.1f*gx, -1000.f), 1000.f);
            o4.y = xi4.y + fminf(fmaxf(0.1f*gy, -1000.f), 1000.f);
            o4.z = xi4.z + fminf(fmaxf(0.1f*gz, -1000.f), 1000.f);
            o4.w = xi4.w + fminf(fmaxf(0.1f*gw, -1000.f), 1000.f);
            ((float4*)out)[i*8 + q] = o4;
        }
    }
}

extern "C" void kernel_launch(void* const* d_in, const int* in_sizes, int n_in,
                              void* d_out, int out_size, void* d_ws, size_t ws_size,
                              hipStream_t stream) {
    const float* particle = (const float*)d_in[0];
    const float* mu       = (const float*)d_in[1];
    float* outp           = (float*)d_out;
    hipLaunchKernelGGL(svgd_kernel, dim3(NB), dim3(NTHREADS), 0, stream,
                       particle, mu, outp);
}

// Round 7
// 14.098 us; speedup vs baseline: 6.1746x; 1.3539x over previous
//
#include <hip/hip_runtime.h>
#include <math.h>

#define NP 64
#define DD 32
#define NTHREADS 1024
#define NB 8            // blocks; each owns 8 output particles
#define NBUK 4096

__device__ __forceinline__ float readlane_f(float v, int lane) {
    return __int_as_float(__builtin_amdgcn_readlane(__float_as_int(v), lane));
}

__global__ __launch_bounds__(NTHREADS)
void svgd_kernel(const float* __restrict__ particle,
                 const float* __restrict__ mu,
                 float* __restrict__ out) {
    __shared__ float    sNarr[NP];
    __shared__ float4   jinfo[NP];       // (sj, 1/sj, -qv_j, 0)
    __shared__ float    dist2[NP*NP];    // 16KB
    __shared__ uint2    wmm[16];         // per-wave (min,max) of tri bits
    __shared__ unsigned hist[NBUK];      // 16KB histogram
    __shared__ unsigned resv[2];         // truncated rank-991 / rank-992 bits
    __shared__ float4   wpart[3*64];
    __shared__ float    kpart[3*64];
    __shared__ float    invdS;

    const int tid  = threadIdx.x;
    const int lane = tid & 63;
    const int wv   = tid >> 6;
    const int i0   = blockIdx.x * 8;

    // clear histogram (before any barrier; overlaps with loads)
    #pragma unroll
    for (int k = 0; k < NBUK/NTHREADS; ++k) hist[tid + k*NTHREADS] = 0u;

    // ---------- P1: rows from global, norms, dist2 (kept in regs) ----------
    float4 xq[8];
    #pragma unroll
    for (int k = 0; k < 8; ++k) xq[k] = ((const float4*)particle)[lane*8 + k];
    float xv[DD];
    #pragma unroll
    for (int k = 0; k < 8; ++k) {
        xv[4*k+0] = xq[k].x; xv[4*k+1] = xq[k].y;
        xv[4*k+2] = xq[k].z; xv[4*k+3] = xq[k].w;
    }
    float sj = 0.f;
    #pragma unroll
    for (int d = 0; d < DD; ++d) sj = fmaf(xv[d], xv[d], sj);

    if (wv == 0) {
        sNarr[lane] = sj;
        float mreg = mu[lane & 31];
        float mdot = 0.f;
        #pragma unroll
        for (int d = 0; d < DD; ++d) mdot = fmaf(readlane_f(mreg, d), xv[d], mdot);
        float inv_sj = 1.0f / sj;
        jinfo[lane] = make_float4(sj, inv_sj, -mdot*inv_sj, 0.f);
    }

    unsigned ubr[4];
    unsigned tmn = 0xFFFFFFFFu, tmx = 0u;
    #pragma unroll
    for (int r = 0; r < 4; ++r) {
        int i = wv*4 + r;
        float acc = 0.f;
        #pragma unroll
        for (int d = 0; d < DD; ++d) acc = fmaf(readlane_f(xv[d], i), xv[d], acc);
        float si = readlane_f(sj, i);
        float d2 = si + sj - 2.f*acc;
        dist2[i*64 + lane] = d2;
        unsigned ub = __float_as_uint(d2);
        ubr[r] = ub;
        if (i < lane) {
            tmn = ub < tmn ? ub : tmn;
            tmx = ub > tmx ? ub : tmx;
        }
    }
    #pragma unroll
    for (int m = 32; m >= 1; m >>= 1) {
        unsigned on = (unsigned)__shfl_xor((int)tmn, m, 64);
        unsigned ox = (unsigned)__shfl_xor((int)tmx, m, 64);
        tmn = on < tmn ? on : tmn;
        tmx = ox > tmx ? ox : tmx;
    }
    if (lane == 0) wmm[wv] = make_uint2(tmn, tmx);
    __syncthreads();                     // B1

    // ---------- P2a: all threads — combine min/max, histogram own values ---
    unsigned mnv = 0xFFFFFFFFu, mx = 0u;
    #pragma unroll
    for (int k = 0; k < 16; ++k) {
        uint2 wm = wmm[k];
        mnv = wm.x < mnv ? wm.x : mnv;
        mx  = wm.y > mx  ? wm.y : mx;
    }
    int shift = 15;
    unsigned range = (mx >> shift) - (mnv >> shift);
    while (range > (unsigned)(NBUK-1)) {
        ++shift;
        range = (mx >> shift) - (mnv >> shift);
    }
    const unsigned base = mnv >> shift;
    #pragma unroll
    for (int r = 0; r < 4; ++r) {
        int i = wv*4 + r;
        if (i < lane) atomicAdd(&hist[(ubr[r] >> shift) - base], 1u);
    }
    __syncthreads();                     // B2

    // ---------- P2b: wave-0 parallel scan to find ranks 991 / 992 ----------
    if (wv == 0) {
        int nb = (int)range + 1;
        int chunk = (nb + 63) >> 6;
        int st = lane * chunk;
        unsigned tot = 0;
        for (int c = 0; c < chunk; ++c) {
            int b = st + c;
            if (b < nb) tot += hist[b];
        }
        unsigned inc = tot;
        #pragma unroll
        for (int m = 1; m < 64; m <<= 1) {
            unsigned o = (unsigned)__shfl_up((int)inc, m, 64);
            if (lane >= m) inc += o;
        }
        unsigned excl = inc - tot;
        #pragma unroll
        for (int rk = 0; rk < 2; ++rk) {
            unsigned target = 991u + (unsigned)rk;
            if (excl <= target && target < excl + tot) {
                unsigned cum = excl; int b = st;
                for (;;) {
                    unsigned c = hist[b];
                    if (cum + c > target) break;
                    cum += c; ++b;
                }
                resv[rk] = (base + (unsigned)b) << shift;
            }
        }
        __builtin_amdgcn_s_waitcnt(0);   // make resv visible within the wave
        if (lane == 0) {
            float med = 0.5f*(__uint_as_float(resv[0]) + __uint_as_float(resv[1]));
            float denom = med * (1.0f/4.1588830833596715f) + 1e-6f;  // /ln(64)+eps
            invdS = 1.0f / denom;
        }
    }
    __syncthreads();                     // B3

    // ---------- P4: fused (K,E) + accumulation, 256 threads ----------------
    {
        const float invd = invdS;
        float4 w4 = make_float4(0.f,0.f,0.f,0.f);
        float  kacc = 0.f;
        if (tid < 256) {
            int h  = tid >> 6;
            int il = (tid >> 3) & 7;
            int q  = tid & 7;
            int i  = i0 + il;
            float si = sNarr[i];
            float4 xr[16];
            #pragma unroll
            for (int jj = 0; jj < 16; ++jj)
                xr[jj] = ((const float4*)particle)[(h*16 + jj)*8 + q];
            #pragma unroll
            for (int jj = 0; jj < 16; ++jj) {
                int j = h*16 + jj;
                float4 ji = jinfo[j];
                float d2  = dist2[j*64 + i];
                float K   = __expf(-d2 * invd);
                float u   = d2 - si - ji.x;
                float t1  = fmaf(invd, u, -(float)(DD-1));
                float E   = K * fmaf(t1, ji.y, ji.z);
                float4 x4 = xr[jj];
                w4.x = fmaf(E, x4.x, w4.x);
                w4.y = fmaf(E, x4.y, w4.y);
                w4.z = fmaf(E, x4.z, w4.z);
                w4.w = fmaf(E, x4.w, w4.w);
                kacc += K;
            }
            if (h > 0) {
                wpart[(h-1)*64 + (tid & 63)] = w4;
                kpart[(h-1)*64 + (tid & 63)] = kacc;
            }
        }
        __syncthreads();                 // B4
        if (tid < 64) {
            #pragma unroll
            for (int p = 0; p < 3; ++p) {
                float4 wp = wpart[p*64 + tid];
                w4.x += wp.x; w4.y += wp.y; w4.z += wp.z; w4.w += wp.w;
                kacc += kpart[p*64 + tid];
            }
            int il = tid >> 3, q = tid & 7;
            int i  = i0 + il;
            float4 xi4 = ((const float4*)particle)[i*8 + q];
            float4 mu4 = ((const float4*)mu)[q];
            float4 ji  = jinfo[i];       // .y = 1/si
            float  c2  = 2.f*invd*kacc;
            w4.x += kacc*mu4.x + c2*xi4.x;
            w4.y += kacc*mu4.y + c2*xi4.y;
            w4.z += kacc*mu4.z + c2*xi4.z;
            w4.w += kacc*mu4.w + c2*xi4.w;
            float rdot = xi4.x*w4.x + xi4.y*w4.y + xi4.z*w4.z + xi4.w*w4.w;
            rdot += __shfl_xor(rdot, 1, 64);
            rdot += __shfl_xor(rdot, 2, 64);
            rdot += __shfl_xor(rdot, 4, 64);
            float s3 = (rdot + (float)(DD-1)) * ji.y;
            float gx = (w4.x - xi4.x*s3) * (1.f/(float)NP);
            float gy = (w4.y - xi4.y*s3) * (1.f/(float)NP);
            float gz = (w4.z - xi4.z*s3) * (1.f/(float)NP);
            float gw = (w4.w - xi4.w*s3) * (1.f/(float)NP);
            float4 o4;
            o4.x = xi4.x + fminf(fmaxf(0.1f*gx, -1000.f), 1000.f);
            o4.y = xi4.y + fminf(fmaxf(0.1f*gy, -1000.f), 1000.f);
            o4.z = xi4.z + fminf(fmaxf(0.1f*gz, -1000.f), 1000.f);
            o4.w = xi4.w + fminf(fmaxf(0.1f*gw, -1000.f), 1000.f);
            ((float4*)out)[i*8 + q] = o4;
        }
    }
}

extern "C" void kernel_launch(void* const* d_in, const int* in_sizes, int n_in,
                              void* d_out, int out_size, void* d_ws, size_t ws_size,
                              hipStream_t stream) {
    const float* particle = (const float*)d_in[0];
    const float* mu       = (const float*)d_in[1];
    float* outp           = (float*)d_out;
    hipLaunchKernelGGL(svgd_kernel, dim3(NB), dim3(NTHREADS), 0, stream,
                       particle, mu, outp);
}